// Round 16
// baseline (325.339 us; speedup 1.0000x reference)
//
#include <hip/hip_runtime.h>

// Problem constants (from reference)
#define B_   16
#define OC_  10
#define N_   256
#define O_   2560   // OC_*N_
#define S_   64     // synapses
#define T_   512
#define KS_  48
#define TP_  561    // T + KS + 1
#define TT   24     // (fallback conv) time steps per thread
#define WROW 72     // (fallback conv) LDS row stride

// B-stationary 32x32 GEMM constants
#define NOC32  80           // o-chunks of 32 outputs
#define XLROWS 336          // local xT rows per m-half (288 + 47 window + 1)
#define JC     6            // j's staged per phase
#define NPH    (KS_/JC)     // 8 phases

#define SCH    16           // neurons per scan block = one 64-B pot line
#define CPITCH 572          // scan LDS row pitch (143 dwords, gcd(143,32)=1)

using i32x4  = __attribute__((ext_vector_type(4))) int;
using i32x16 = __attribute__((ext_vector_type(16))) int;

// ===========================================================================
// prep_all: one dispatch, grid-split.
//  - blocks [0, 2048):    x [16][64][512] f32 -> xb [16][512][64] {0,1}
//  - blocks [2048, 32768): taps -> three signed base-256 digits (22-bit fixed
//    point) into Bg[oc32][j][row=d*32+(o&31)][64] with the 16-B chunk XOR
//    swizzle baked into the GLOBAL layout (chunk p at p ^ (((o&31)>>1)&3);
//    key identical for all 3 digit rows since they differ by 32-row steps)
//    -> conflict-free b128 LDS reads in the gemm (r5/r9-verified bijection).
// ===========================================================================
__global__ void prep_all(const float* __restrict__ x, const float* __restrict__ w,
                         unsigned char* __restrict__ xb, signed char* __restrict__ Bg) {
    if (blockIdx.x < 2048) {
        int idx = blockIdx.x * 256 + threadIdx.x;   // < 524288 exactly
        int t = idx & 511;
        int bi = idx >> 9;
        int i = bi & 63, b = bi >> 6;
        xb[((size_t)(b * 512 + t) << 6) + i] = (x[idx] != 0.0f) ? 1 : 0;
    } else {
        int idx = (blockIdx.x - 2048) * 256 + threadIdx.x;  // < 7,864,320 exactly
        int i = idx & 63;
        int oj = idx >> 6;
        int j = oj % KS_, o = oj / KS_;
        float wv = w[(o << 6) + i];
        float rise = (float)j * 0.0625f;
        float leak = -((float)j - wv * 16.0f) * 0.03125f + wv;
        float kv   = fmaxf(0.0f, fminf(rise, leak));     // in [0,1]
        int q  = (int)lrintf(kv * 4194304.0f);           // kv * 2^22
        int d0 = ((q + 128) & 255) - 128;                // [-128,127]
        int q1 = (q - d0) >> 8;
        int d1 = ((q1 + 128) & 255) - 128;               // [-128,127]
        int d2 = (q1 - d1) >> 8;                         // [0,64]
        int oc = o >> 5, ol = o & 31;
        int key = (ol >> 1) & 3;
        int bpos = ((((i >> 4) ^ key) << 4) | (i & 15)); // swizzled byte in row
        size_t base = (((size_t)(oc * KS_ + j) * 96) + ol) * 64 + bpos;
        Bg[base]            = (signed char)d0;           // row ol
        Bg[base + 32 * 64]  = (signed char)d1;           // row 32+ol
        Bg[base + 64 * 64]  = (signed char)d2;           // row 64+ol
    }
}

// ===========================================================================
// gemm_i8 (32x32x32 shape): block = (oc32, b, m-half), 192 threads (3 waves),
// wave handles 3 m-tiles of 32 t x (32 outputs x 3 digits).  x[b] m-half
// resident in LDS (336 rows x 64 B, chunk p at p^((rl>>1)&3)); B staged 6 j's
// (36.9 KB) per phase, single buffer.  Per j per wave: 12 ds_read_b128 serve
// 18 dual-K MFMAs (~659 matrix-cyc) -> decisively MFMA-bound.
// A-frag: row=lane&31, k=(lane>>5)*16+byte (16 contiguous B).  C/D:
// col=lane&31 (=output), row=(reg&3)+8*(reg>>2)+4*(lane>>5) (m74-verified).
// mfma_i32_32x32x32_i8, exact int32 accumulation, in-lane digit combine.
// ===========================================================================
__global__ __launch_bounds__(192, 2) void gemm_i8(
    const unsigned char* __restrict__ xb,   // [16][512][64]
    const signed char*  __restrict__ Bg,    // [80][48][96][64] swizzled
    float* __restrict__ pot)                // [B_*TP_][O_]
{
    __shared__ __align__(16) unsigned char xT[XLROWS * 64];    // 21,504 B
    __shared__ __align__(16) signed char  Bst[JC * 96 * 64];   // 36,864 B

    const int tid  = threadIdx.x;
    const int lane = tid & 63;
    const int wave = tid >> 6;             // 0..2
    const int oc = blockIdx.x;             // 0..79
    const int b  = blockIdx.y;             // 0..15
    const int mh = blockIdx.z;             // 0..1 (m-half: t in [mh*288, +288))
    const int l31 = lane & 31;
    const int lh  = lane >> 5;             // k-half selector
    const int keyB = (l31 >> 1) & 3;       // Bst swizzle key (row = d*32+l31)

    const signed char* BgBase = Bg + (size_t)oc * (KS_ * 96 * 64);

    // stage one phase (6 j's = 36,864 B = 2304 chunks, 12/thread) into Bst
    auto stage = [&](int ph) {
        const signed char* src = BgBase + (size_t)(ph * JC) * 96 * 64;
        for (int c = tid; c < JC * 96 * 64 / 16; c += 192)
            __builtin_amdgcn_global_load_lds(
                (const __attribute__((address_space(1))) void*)(src + c * 16),
                (__attribute__((address_space(3))) void*)(Bst + c * 16),
                16, 0, 0);
    };

    stage(0);   // overlaps with xT fill below

    // xT fill: local row rl <-> global row r = mh*288 + rl; data rows are
    // r in [49,560] <- x[b][r-49]; others zero.  Chunk p at p ^ ((rl>>1)&3)
    // (288 = 0 mod 8, so local key == global key).
    const unsigned char* xbb = xb + ((size_t)b << 15);   // 512*64 bytes
    for (int c = tid; c < XLROWS * 4; c += 192) {
        int rl = c >> 2, p = c & 3;
        int r = mh * 288 + rl;
        i32x4 v = (i32x4){0, 0, 0, 0};
        if (r >= 49 && r <= 560) v = *(const i32x4*)(xbb + (size_t)(r - 49) * 64 + p * 16);
        *(i32x4*)(xT + rl * 64 + ((p ^ ((rl >> 1) & 3)) << 4)) = v;
    }

    i32x16 acc[3][3];                      // [m-tile][digit]
#pragma unroll
    for (int mt = 0; mt < 3; ++mt)
#pragma unroll
        for (int d = 0; d < 3; ++d)
#pragma unroll
            for (int r = 0; r < 16; ++r)
                acc[mt][d][r] = 0;

    __syncthreads();   // xT writes + phase-0 staging drained

    for (int ph = 0; ph < NPH; ++ph) {
#pragma unroll
        for (int jl = 0; jl < JC; ++jl) {
            const int j = ph * JC + jl;
            // A rows: rl = wave*96 + l31 + 48 - j + mt*32; +32 preserves
            // (rl>>1)&3 -> one key per (lane, j)
            const int rbase = wave * 96 + l31 + 48 - j;
            const int keyA = (rbase >> 1) & 3;
            i32x4 af[3][2], bf[3][2];
#pragma unroll
            for (int mt = 0; mt < 3; ++mt)
#pragma unroll
                for (int kc = 0; kc < 2; ++kc)
                    af[mt][kc] = *(const i32x4*)
                        (xT + (rbase + mt * 32) * 64 + (((kc * 2 + lh) ^ keyA) << 4));
#pragma unroll
            for (int d = 0; d < 3; ++d)
#pragma unroll
                for (int kc = 0; kc < 2; ++kc)
                    bf[d][kc] = *(const i32x4*)
                        (Bst + (size_t)(jl * 96 + d * 32 + l31) * 64
                             + (((kc * 2 + lh) ^ keyB) << 4));
#pragma unroll
            for (int mt = 0; mt < 3; ++mt)
#pragma unroll
                for (int d = 0; d < 3; ++d)
#pragma unroll
                    for (int kc = 0; kc < 2; ++kc)
                        acc[mt][d] = __builtin_amdgcn_mfma_i32_32x32x32_i8(
                            af[mt][kc], bf[d][kc], acc[mt][d], 0, 0, 0);
        }
        __syncthreads();               // all waves done reading Bst
        if (ph + 1 < NPH) {
            stage(ph + 1);
            __syncthreads();           // staging drained before reads
        }
    }

    // epilogue: C/D col=lane&31 (output), row=(reg&3)+8*(reg>>2)+4*lh (t);
    // digits in-lane -> exact double combine.
    const size_t potb = (size_t)b * TP_;
    const int oo = oc * 32 + l31;
#pragma unroll
    for (int mt = 0; mt < 3; ++mt) {
#pragma unroll
        for (int reg = 0; reg < 16; ++reg) {
            int t = mh * 288 + wave * 96 + mt * 32
                  + (reg & 3) + 8 * (reg >> 2) + 4 * lh;
            if (t < TP_) {
                double pq = ((double)acc[mt][0][reg]
                           + 256.0   * (double)acc[mt][1][reg]
                           + 65536.0 * (double)acc[mt][2][reg])
                          * (1.0 / 4194304.0);
                pot[(potb + t) * O_ + oo] = (float)pq;
            }
        }
    }
}

// ===========================================================================
// scan_fused (r15, measured good): memset + scan_prep + scan_run in ONE
// kernel.  block = (nc, b): SCH=16 neurons (one full 64-B pot line per read)
// x 1024 threads (16 waves/CU at 256 blocks).
// ===========================================================================
__global__ __launch_bounds__(1024) void scan_fused(
    const float* __restrict__ pot,    // [B_*TP_][O_]
    float* __restrict__ out)          // [B_][OC_][N_][TP_]
{
    __shared__ unsigned char codeW[SCH * CPITCH];   // [nl][t]
    __shared__ unsigned char ocW[SCH * CPITCH];

    const int tid = threadIdx.x;
    const int nc = blockIdx.x;        // 0..15 (neuron chunk of 16)
    const int b  = blockIdx.y;        // 0..15
    const int n0 = nc * SCH;

    // P1: per (t, nl) argmax over 10 channels + threshold
    for (int pair = tid; pair < TP_ * SCH; pair += 1024) {
        int t = pair >> 4, nl = pair & 15;
        const float* p = pot + ((size_t)(b * TP_ + t)) * O_ + n0 + nl;
        float best = p[0]; int bo = 0;
#pragma unroll
        for (int ch = 1; ch < OC_; ++ch) {
            float v = p[ch * N_];
            if (v > best) { best = v; bo = ch; }   // strict >: FIRST max wins
        }
        codeW[nl * CPITCH + t] =
            ((best + 16.0f) > 32.0f) ? (unsigned char)(bo + 1) : (unsigned char)0;
        ocW[nl * CPITCH + t] = 0;
    }
    __syncthreads();

    // P2: depression walk, lanes 0..15, batched 48-B LDS reads
    if (tid < SCH) {
        const unsigned char* c = &codeW[tid * CPITCH];
        unsigned char* o = &ocW[tid * CPITCH];
        int t = 0;
        while (t < TP_) {
            unsigned char buf[KS_];
#pragma unroll
            for (int k = 0; k < KS_; ++k) {
                int tt = t + k;
                buf[k] = (tt < TP_) ? c[tt] : (unsigned char)0;
            }
            int adv = KS_;
#pragma unroll
            for (int k = 0; k < KS_; ++k) {
                if (buf[k]) { o[t + k] = buf[k]; adv = k + KS_; break; }
            }
            t += adv;
        }
    }
    __syncthreads();

    // P3: dense output write: out[b][ch][n0+nl][t]
    float* ob = out + (((size_t)b * OC_) * N_ + n0) * TP_;
    for (int idx = tid; idx < OC_ * SCH * TP_; idx += 1024) {
        int r = idx / TP_;            // r = ch*16 + nl
        int t = idx - r * TP_;
        int ch = r >> 4, nl = r & 15;
        float v = (ocW[nl * CPITCH + t] == (unsigned char)(ch + 1)) ? 1.0f : 0.0f;
        ob[((size_t)ch * N_ + nl) * TP_ + t] = v;
    }
}

// ===========================================================================
// FALLBACK (round-1 direct conv) — only if ws_size too small
// ===========================================================================
__global__ void transpose_w(const float* __restrict__ w, float* __restrict__ wT) {
    int idx = blockIdx.x * 256 + threadIdx.x;
    if (idx >= O_ * S_) return;
    int o = idx >> 6, i = idx & 63;
    wT[i * O_ + o] = w[idx];
}

__global__ __launch_bounds__(256) void conv_kernel(
    const float* __restrict__ x, const float* __restrict__ wT,
    float* __restrict__ pot)
{
    const int b  = blockIdx.y;
    const int t0 = blockIdx.z * TT;
    const int o  = blockIdx.x * 256 + threadIdx.x;

    __shared__ __align__(16) float xsh[S_][WROW];
    for (int idx = threadIdx.x; idx < S_ * WROW; idx += 256) {
        int i = idx / WROW, m = idx - i * WROW;
        int t = t0 - KS_ + m;
        float v = 0.0f;
        if (t >= 0 && t < T_) v = x[(b * S_ + i) * T_ + t];
        xsh[i][m] = v;
    }
    __syncthreads();

    float acch[TT], accl[TT];
#pragma unroll
    for (int tl = 0; tl < TT; ++tl) { acch[tl] = 0.0f; accl[tl] = 0.0f; }

    for (int i = 0; i < S_; ++i) {
        float xw[WROW];
#pragma unroll
        for (int w4 = 0; w4 < WROW / 4; ++w4) {
            const float4 v = *reinterpret_cast<const float4*>(&xsh[i][w4 * 4]);
            xw[w4 * 4 + 0] = v.x; xw[w4 * 4 + 1] = v.y;
            xw[w4 * 4 + 2] = v.z; xw[w4 * 4 + 3] = v.w;
        }
        const float wv = wT[i * O_ + o];
#pragma unroll
        for (int j = 1; j < KS_; ++j) {
            float rise = (float)j * 0.0625f;
            float leak = -((float)j - wv * 16.0f) * 0.03125f + wv;
            float kv   = fmaxf(0.0f, fminf(rise, leak));
            float khi  = rintf(kv * 4096.0f) * 2.44140625e-4f;
            float klo  = kv - khi;
#pragma unroll
            for (int tl = 0; tl < TT; ++tl) {
                float xv = xw[tl + (KS_ - 1) - j];
                acch[tl] = fmaf(xv, khi, acch[tl]);
                accl[tl] = fmaf(xv, klo, accl[tl]);
            }
        }
    }
#pragma unroll
    for (int tl = 0; tl < TT; ++tl) {
        int t = t0 + tl;
        if (t < TP_) pot[((size_t)b * TP_ + t) * O_ + o] = acch[tl] + accl[tl];
    }
}

__global__ void scan_prep(const float* __restrict__ pot, unsigned char* __restrict__ code) {
    int idx = blockIdx.x * 256 + threadIdx.x;
    if (idx >= B_ * TP_ * N_) return;
    int n  = idx & (N_ - 1);
    int bt = idx >> 8;
    const float* p = pot + (size_t)bt * O_ + n;
    float best = p[0]; int bo = 0;
#pragma unroll
    for (int oc = 1; oc < OC_; ++oc) {
        float v = p[oc * N_];
        if (v > best) { best = v; bo = oc; }
    }
    code[idx] = ((best + 16.0f) > 32.0f) ? (unsigned char)(bo + 1) : (unsigned char)0;
}

__global__ void scan_run(const unsigned char* __restrict__ code, float* __restrict__ out) {
    int idx = blockIdx.x * 256 + threadIdx.x;
    if (idx >= B_ * N_) return;
    int b = idx >> 8, n = idx & 255;
    const unsigned char* c = code + (size_t)b * TP_ * N_ + n;
    int t = 0;
    while (t < TP_) {
        unsigned char buf[KS_];
#pragma unroll
        for (int k = 0; k < KS_; ++k) {
            int tt = t + k;
            buf[k] = (tt < TP_) ? c[(size_t)tt * N_] : (unsigned char)0;
        }
        int adv = KS_;
#pragma unroll
        for (int k = 0; k < KS_; ++k) {
            if (buf[k]) {
                out[(((size_t)b * OC_ + (buf[k] - 1)) * N_ + n) * TP_ + (t + k)] = 1.0f;
                adv = k + KS_;
                break;
            }
        }
        t += adv;
    }
}

// ===========================================================================
extern "C" void kernel_launch(void* const* d_in, const int* in_sizes, int n_in,
                              void* d_out, int out_size, void* d_ws, size_t ws_size,
                              hipStream_t stream) {
    const float* x = (const float*)d_in[0];   // [16][1][64][512] binary
    const float* w = (const float*)d_in[1];   // [2560][64]
    float* out = (float*)d_out;               // [16][10][256][561]

    char* ws = (char*)d_ws;
    const size_t szX = (size_t)B_ * T_ * S_;                    //     524,288
    const size_t szB = (size_t)NOC32 * KS_ * 96 * 64;           //  23,592,960
    const size_t szP = (size_t)B_ * TP_ * O_ * 4;               //  91,914,240
    const size_t szC = (size_t)B_ * TP_ * N_;                   //   2,297,856
    const size_t need = szX + szB + szP + szC;                  // ~118.3 MB

    if (ws_size >= need) {
        unsigned char* xb  = (unsigned char*)ws;
        signed char* Bg    = (signed char*)(ws + szX);
        float* pot         = (float*)(ws + szX + szB);

        prep_all<<<2048 + 30720, 256, 0, stream>>>(x, w, xb, Bg);
        gemm_i8<<<dim3(NOC32, B_, 2), 192, 0, stream>>>(xb, Bg, pot);
        scan_fused<<<dim3(N_ / SCH, B_), 1024, 0, stream>>>(pot, out);
    } else {
        // fallback: round-1 direct conv (needs ~95 MB)
        size_t pot_bytes  = (size_t)B_ * TP_ * O_ * sizeof(float);
        size_t code_bytes = (size_t)B_ * TP_ * N_;
        float* pot = (float*)ws;
        unsigned char* code = (unsigned char*)(ws + pot_bytes);
        float* wT = (float*)(ws + pot_bytes + code_bytes);

        hipMemsetAsync(d_out, 0, (size_t)out_size * sizeof(float), stream);
        transpose_w<<<(O_ * S_ + 255) / 256, 256, 0, stream>>>(w, wT);
        conv_kernel<<<dim3(O_ / 256, B_, (TP_ + TT - 1) / TT), 256, 0, stream>>>(x, wT, pot);
        scan_prep<<<(B_ * TP_ * N_ + 255) / 256, 256, 0, stream>>>(pot, code);
        scan_run<<<(B_ * N_ + 255) / 256, 256, 0, stream>>>(code, out);
    }
}

// Round 17
// 269.624 us; speedup vs baseline: 1.2066x; 1.2066x over previous
//
#include <hip/hip_runtime.h>

// Problem constants (from reference)
#define B_   16
#define OC_  10
#define N_   256
#define O_   2560   // OC_*N_
#define S_   64     // synapses
#define T_   512
#define KS_  48
#define TP_  561    // T + KS + 1
#define TT   24     // (fallback conv) time steps per thread
#define WROW 72     // (fallback conv) LDS row stride

// B-stationary GEMM constants
#define NOC   160           // o-chunks of 16 outputs
#define XROWS 624           // xT rows: t' + 48 - j range, zero-padded
#define JC    12            // j's staged per phase (4 triples {j0,j0+16,j0+32})
#define NPH   (KS_/JC)      // 4 phases

#define SCH    16           // neurons per scan block = one 64-B pot line
#define CPITCH 572          // scan LDS row pitch (143 dwords, gcd(143,32)=1)

using i32x4 = __attribute__((ext_vector_type(4))) int;

// ===========================================================================
// prep_all: one dispatch, grid-split.
//  - blocks [0, 2048):    x [16][64][512] f32 -> xb [16][512][64] {0,1}
//  - blocks [2048, 32768): taps -> three signed base-256 digits (22-bit fixed
//    point) into Bg[oc][pos][row=d*16+ol][64], pos = (jm>>2)*12 + (jm&3)*3 + jh
//    (groups each phase's 4 triples {j0,j0+16,j0+32} contiguously for the
//    gemm's A-window reuse).  16-B chunk XOR swizzle baked into the GLOBAL
//    layout (chunk p at p ^ ((ol>>1)&3)) -> conflict-free b128 LDS reads.
// ===========================================================================
__global__ void prep_all(const float* __restrict__ x, const float* __restrict__ w,
                         unsigned char* __restrict__ xb, signed char* __restrict__ Bg) {
    if (blockIdx.x < 2048) {
        int idx = blockIdx.x * 256 + threadIdx.x;   // < 524288 exactly
        int t = idx & 511;
        int bi = idx >> 9;
        int i = bi & 63, b = bi >> 6;
        xb[((size_t)(b * 512 + t) << 6) + i] = (x[idx] != 0.0f) ? 1 : 0;
    } else {
        int idx = (blockIdx.x - 2048) * 256 + threadIdx.x;  // < 7,864,320 exactly
        int i = idx & 63;
        int oj = idx >> 6;
        int j = oj % KS_, o = oj / KS_;
        float wv = w[(o << 6) + i];
        float rise = (float)j * 0.0625f;
        float leak = -((float)j - wv * 16.0f) * 0.03125f + wv;
        float kv   = fmaxf(0.0f, fminf(rise, leak));     // in [0,1]
        int q  = (int)lrintf(kv * 4194304.0f);           // kv * 2^22
        int d0 = ((q + 128) & 255) - 128;                // [-128,127]
        int q1 = (q - d0) >> 8;
        int d1 = ((q1 + 128) & 255) - 128;               // [-128,127]
        int d2 = (q1 - d1) >> 8;                         // [0,64]
        int oc = o >> 4, ol = o & 15;
        int jm = j & 15, jh = j >> 4;
        int pos = (jm >> 2) * 12 + (jm & 3) * 3 + jh;    // triple-grouped order
        int key = (ol >> 1) & 3;
        int bpos = ((((i >> 4) ^ key) << 4) | (i & 15)); // swizzled byte in row
        size_t base = (((size_t)(oc * KS_ + pos) * 48) + ol) * 64 + bpos;
        Bg[base]            = (signed char)d0;           // row ol
        Bg[base + 16 * 64]  = (signed char)d1;           // row 16+ol
        Bg[base + 32 * 64]  = (signed char)d2;           // row 32+ol
    }
}

// ===========================================================================
// gemm_i8 (r11 structure — measured best): B-stationary, triple-j A-reuse,
// JC=12 single-buffered.  block = (oc, b); x[b] resident in LDS (64-B rows,
// chunk p at p^((row>>1)&3)); B staged 12 j's per phase as 4 triples.
// Per triple: 11 A-reads + 9 B-reads serve 81 MFMAs.  Conflict-free b128.
// mfma_i32_16x16x64_i8, exact int32 accumulation, in-lane digit combine.
// ===========================================================================
__global__ __launch_bounds__(256, 2) void gemm_i8(
    const unsigned char* __restrict__ xb,   // [16][512][64]
    const signed char*  __restrict__ Bg,    // [NOC][48][48][64] permuted+swizzled
    float* __restrict__ pot)                // [B_*TP_][O_]
{
    __shared__ __align__(16) unsigned char xT[XROWS * 64];     // 39,936 B
    __shared__ __align__(16) signed char  Bst[JC * 48 * 64];   // 36,864 B

    const int tid  = threadIdx.x;
    const int lane = tid & 63;
    const int wave = tid >> 6;
    const int oc = blockIdx.x;             // 0..159
    const int b  = blockIdx.y;             // 0..15
    const int lrow = lane & 15;
    const int quad = lane >> 4;
    const int tw = wave * 144;             // wave m-base (t)
    const int coffB = ((quad ^ ((lrow >> 1) & 3)) << 4);  // Bst swizzled chunk

    const signed char* BgBase = Bg + (size_t)oc * KS_ * 48 * 64;

    auto stage = [&](int ph) {
        const signed char* src = BgBase + (size_t)(ph * JC) * 48 * 64;
        for (int c = tid; c < JC * 48 * 64 / 16; c += 256)
            __builtin_amdgcn_global_load_lds(
                (const __attribute__((address_space(1))) void*)(src + c * 16),
                (__attribute__((address_space(3))) void*)(Bst + c * 16),
                16, 0, 0);
    };

    stage(0);   // overlaps with xT fill below

    // xT fill: zero ONLY pad rows (0..48, 561..623); data rows 49..560 <- x[b]
    for (int z = tid; z < 112 * 4; z += 256) {
        int zi = z >> 2, p = z & 3;
        int r = (zi < 49) ? zi : (561 + zi - 49);
        *(i32x4*)(xT + r * 64 + p * 16) = (i32x4){0, 0, 0, 0};
    }
    const unsigned char* xbb = xb + ((size_t)b << 15);   // 512*64 bytes
    for (int q = tid; q < 2048; q += 256) {              // 16-B chunks
        i32x4 v = *(const i32x4*)(xbb + q * 16);
        int t = q >> 2, p = q & 3;
        int r = 49 + t;
        *(i32x4*)(xT + r * 64 + ((p ^ ((r >> 1) & 3)) << 4)) = v;
    }

    i32x4 acc[9][3];
#pragma unroll
    for (int mi = 0; mi < 9; ++mi)
#pragma unroll
        for (int f = 0; f < 3; ++f)
            acc[mi][f] = (i32x4){0, 0, 0, 0};

    __syncthreads();   // xT writes + phase-0 staging drained

    for (int ph = 0; ph < NPH; ++ph) {
#pragma unroll
        for (int tloc = 0; tloc < 4; ++tloc) {
            const int j0 = ph * 4 + tloc;          // jm of this triple
            const int rb = tw + 16 - j0 + lrow;
            const int coffA = ((quad ^ ((rb >> 1) & 3)) << 4);
            i32x4 af[11], bf[3][3];
#pragma unroll
            for (int k = 0; k < 11; ++k)
                af[k] = *(const i32x4*)(xT + (rb + k * 16) * 64 + coffA);
#pragma unroll
            for (int jh = 0; jh < 3; ++jh)
#pragma unroll
                for (int f = 0; f < 3; ++f)
                    bf[jh][f] = *(const i32x4*)
                        (Bst + (((tloc * 3 + jh) * 48) + f * 16 + lrow) * 64 + coffB);
#pragma unroll
            for (int jh = 0; jh < 3; ++jh)
#pragma unroll
                for (int mi = 0; mi < 9; ++mi)
#pragma unroll
                    for (int f = 0; f < 3; ++f)
                        acc[mi][f] = __builtin_amdgcn_mfma_i32_16x16x64_i8(
                            af[mi + 2 - jh], bf[jh][f], acc[mi][f], 0, 0, 0);
        }
        __syncthreads();               // all waves done reading Bst
        if (ph + 1 < NPH) {
            stage(ph + 1);
            __syncthreads();           // staging drained before reads
        }
    }

    // epilogue: C/D col=lane&15 (ol), row=quad*4+r (t); digits in-lane
    const size_t potb = (size_t)b * TP_;
#pragma unroll
    for (int mi = 0; mi < 9; ++mi) {
#pragma unroll
        for (int r = 0; r < 4; ++r) {
            int t = tw + mi * 16 + quad * 4 + r;
            if (t < TP_) {
                double pq = ((double)acc[mi][0][r]
                           + 256.0   * (double)acc[mi][1][r]
                           + 65536.0 * (double)acc[mi][2][r])
                          * (1.0 / 4194304.0);
                pot[(potb + t) * O_ + oc * 16 + lrow] = (float)pq;
            }
        }
    }
}

// ===========================================================================
// scan_fused: memset + scan_prep + scan_run in ONE kernel.
// block = (nc, b): SCH=16 neurons (one full 64-B pot line per read -> no
// inter-XCD over-fetch) x 1024 threads (16 waves/CU at 256 blocks).
//  P1: argmax/threshold from pot -> codeW[nl][t] in LDS (bit-identical
//      decisions to the reference scan).
//  P2: 16 lanes walk the depression counter in-register over 48-B LDS
//      batches (advance >= 48 per batch) -> ocW[nl][t] = winner+1 or 0.
//  P3: all threads densely write the 10x16x561 output tile (every element
//      written -> no separate d_out memset dispatch needed).
// ===========================================================================
__global__ __launch_bounds__(1024) void scan_fused(
    const float* __restrict__ pot,    // [B_*TP_][O_]
    float* __restrict__ out)          // [B_][OC_][N_][TP_]
{
    __shared__ unsigned char codeW[SCH * CPITCH];   // [nl][t]
    __shared__ unsigned char ocW[SCH * CPITCH];

    const int tid = threadIdx.x;
    const int nc = blockIdx.x;        // 0..15 (neuron chunk of 16)
    const int b  = blockIdx.y;        // 0..15
    const int n0 = nc * SCH;

    // P1: per (t, nl) argmax over 10 channels + threshold
    for (int pair = tid; pair < TP_ * SCH; pair += 1024) {
        int t = pair >> 4, nl = pair & 15;
        const float* p = pot + ((size_t)(b * TP_ + t)) * O_ + n0 + nl;
        float best = p[0]; int bo = 0;
#pragma unroll
        for (int ch = 1; ch < OC_; ++ch) {
            float v = p[ch * N_];
            if (v > best) { best = v; bo = ch; }   // strict >: FIRST max wins
        }
        codeW[nl * CPITCH + t] =
            ((best + 16.0f) > 32.0f) ? (unsigned char)(bo + 1) : (unsigned char)0;
        ocW[nl * CPITCH + t] = 0;
    }
    __syncthreads();

    // P2: depression walk, lanes 0..15, batched 48-B LDS reads
    if (tid < SCH) {
        const unsigned char* c = &codeW[tid * CPITCH];
        unsigned char* o = &ocW[tid * CPITCH];
        int t = 0;
        while (t < TP_) {
            unsigned char buf[KS_];
#pragma unroll
            for (int k = 0; k < KS_; ++k) {
                int tt = t + k;
                buf[k] = (tt < TP_) ? c[tt] : (unsigned char)0;
            }
            int adv = KS_;
#pragma unroll
            for (int k = 0; k < KS_; ++k) {
                if (buf[k]) { o[t + k] = buf[k]; adv = k + KS_; break; }
            }
            t += adv;
        }
    }
    __syncthreads();

    // P3: dense output write: out[b][ch][n0+nl][t]
    float* ob = out + (((size_t)b * OC_) * N_ + n0) * TP_;
    for (int idx = tid; idx < OC_ * SCH * TP_; idx += 1024) {
        int r = idx / TP_;            // r = ch*16 + nl
        int t = idx - r * TP_;
        int ch = r >> 4, nl = r & 15;
        float v = (ocW[nl * CPITCH + t] == (unsigned char)(ch + 1)) ? 1.0f : 0.0f;
        ob[((size_t)ch * N_ + nl) * TP_ + t] = v;
    }
}

// ===========================================================================
// FALLBACK (round-1 direct conv) — only if ws_size too small
// ===========================================================================
__global__ void transpose_w(const float* __restrict__ w, float* __restrict__ wT) {
    int idx = blockIdx.x * 256 + threadIdx.x;
    if (idx >= O_ * S_) return;
    int o = idx >> 6, i = idx & 63;
    wT[i * O_ + o] = w[idx];
}

__global__ __launch_bounds__(256) void conv_kernel(
    const float* __restrict__ x, const float* __restrict__ wT,
    float* __restrict__ pot)
{
    const int b  = blockIdx.y;
    const int t0 = blockIdx.z * TT;
    const int o  = blockIdx.x * 256 + threadIdx.x;

    __shared__ __align__(16) float xsh[S_][WROW];
    for (int idx = threadIdx.x; idx < S_ * WROW; idx += 256) {
        int i = idx / WROW, m = idx - i * WROW;
        int t = t0 - KS_ + m;
        float v = 0.0f;
        if (t >= 0 && t < T_) v = x[(b * S_ + i) * T_ + t];
        xsh[i][m] = v;
    }
    __syncthreads();

    float acch[TT], accl[TT];
#pragma unroll
    for (int tl = 0; tl < TT; ++tl) { acch[tl] = 0.0f; accl[tl] = 0.0f; }

    for (int i = 0; i < S_; ++i) {
        float xw[WROW];
#pragma unroll
        for (int w4 = 0; w4 < WROW / 4; ++w4) {
            const float4 v = *reinterpret_cast<const float4*>(&xsh[i][w4 * 4]);
            xw[w4 * 4 + 0] = v.x; xw[w4 * 4 + 1] = v.y;
            xw[w4 * 4 + 2] = v.z; xw[w4 * 4 + 3] = v.w;
        }
        const float wv = wT[i * O_ + o];
#pragma unroll
        for (int j = 1; j < KS_; ++j) {
            float rise = (float)j * 0.0625f;
            float leak = -((float)j - wv * 16.0f) * 0.03125f + wv;
            float kv   = fmaxf(0.0f, fminf(rise, leak));
            float khi  = rintf(kv * 4096.0f) * 2.44140625e-4f;
            float klo  = kv - khi;
#pragma unroll
            for (int tl = 0; tl < TT; ++tl) {
                float xv = xw[tl + (KS_ - 1) - j];
                acch[tl] = fmaf(xv, khi, acch[tl]);
                accl[tl] = fmaf(xv, klo, accl[tl]);
            }
        }
    }
#pragma unroll
    for (int tl = 0; tl < TT; ++tl) {
        int t = t0 + tl;
        if (t < TP_) pot[((size_t)b * TP_ + t) * O_ + o] = acch[tl] + accl[tl];
    }
}

__global__ void scan_prep(const float* __restrict__ pot, unsigned char* __restrict__ code) {
    int idx = blockIdx.x * 256 + threadIdx.x;
    if (idx >= B_ * TP_ * N_) return;
    int n  = idx & (N_ - 1);
    int bt = idx >> 8;
    const float* p = pot + (size_t)bt * O_ + n;
    float best = p[0]; int bo = 0;
#pragma unroll
    for (int oc = 1; oc < OC_; ++oc) {
        float v = p[oc * N_];
        if (v > best) { best = v; bo = oc; }
    }
    code[idx] = ((best + 16.0f) > 32.0f) ? (unsigned char)(bo + 1) : (unsigned char)0;
}

__global__ void scan_run(const unsigned char* __restrict__ code, float* __restrict__ out) {
    int idx = blockIdx.x * 256 + threadIdx.x;
    if (idx >= B_ * N_) return;
    int b = idx >> 8, n = idx & 255;
    const unsigned char* c = code + (size_t)b * TP_ * N_ + n;
    int t = 0;
    while (t < TP_) {
        unsigned char buf[KS_];
#pragma unroll
        for (int k = 0; k < KS_; ++k) {
            int tt = t + k;
            buf[k] = (tt < TP_) ? c[(size_t)tt * N_] : (unsigned char)0;
        }
        int adv = KS_;
#pragma unroll
        for (int k = 0; k < KS_; ++k) {
            if (buf[k]) {
                out[(((size_t)b * OC_ + (buf[k] - 1)) * N_ + n) * TP_ + (t + k)] = 1.0f;
                adv = k + KS_;
                break;
            }
        }
        t += adv;
    }
}

// ===========================================================================
extern "C" void kernel_launch(void* const* d_in, const int* in_sizes, int n_in,
                              void* d_out, int out_size, void* d_ws, size_t ws_size,
                              hipStream_t stream) {
    const float* x = (const float*)d_in[0];   // [16][1][64][512] binary
    const float* w = (const float*)d_in[1];   // [2560][64]
    float* out = (float*)d_out;               // [16][10][256][561]

    char* ws = (char*)d_ws;
    const size_t szX = (size_t)B_ * T_ * S_;                    //     524,288
    const size_t szB = (size_t)NOC * KS_ * 48 * 64;             //  23,592,960
    const size_t szP = (size_t)B_ * TP_ * O_ * 4;               //  91,914,240
    const size_t szC = (size_t)B_ * TP_ * N_;                   //   2,297,856
    const size_t need = szX + szB + szP + szC;                  // ~118.3 MB

    if (ws_size >= need) {
        unsigned char* xb  = (unsigned char*)ws;
        signed char* Bg    = (signed char*)(ws + szX);
        float* pot         = (float*)(ws + szX + szB);

        prep_all<<<2048 + 30720, 256, 0, stream>>>(x, w, xb, Bg);
        gemm_i8<<<dim3(NOC, B_), 256, 0, stream>>>(xb, Bg, pot);
        scan_fused<<<dim3(N_ / SCH, B_), 1024, 0, stream>>>(pot, out);
    } else {
        // fallback: round-1 direct conv (needs ~95 MB)
        size_t pot_bytes  = (size_t)B_ * TP_ * O_ * sizeof(float);
        size_t code_bytes = (size_t)B_ * TP_ * N_;
        float* pot = (float*)ws;
        unsigned char* code = (unsigned char*)(ws + pot_bytes);
        float* wT = (float*)(ws + pot_bytes + code_bytes);

        hipMemsetAsync(d_out, 0, (size_t)out_size * sizeof(float), stream);
        transpose_w<<<(O_ * S_ + 255) / 256, 256, 0, stream>>>(w, wT);
        conv_kernel<<<dim3(O_ / 256, B_, (TP_ + TT - 1) / TT), 256, 0, stream>>>(x, wT, pot);
        scan_prep<<<(B_ * TP_ * N_ + 255) / 256, 256, 0, stream>>>(pot, code);
        scan_run<<<(B_ * N_ + 255) / 256, 256, 0, stream>>>(code, out);
    }
}